// Round 1
// baseline (561.998 us; speedup 1.0000x reference)
//
#include <hip/hip_runtime.h>
#include <hip/hip_bf16.h>
#include <stdint.h>

#define D_MODEL 512
#define N_EXP 8
#define D_FF 2048
#define NTOK 8192
#define NE (NTOK*2)
#define TM 64
#define MAX_TILES (NE/TM + N_EXP)   /* 264 */
#define NEPAD (MAX_TILES*TM)        /* 16896 */

typedef __attribute__((ext_vector_type(8))) short short8;
typedef __attribute__((ext_vector_type(4))) float f32x4;

struct Ctrl {
  int cnt[8];
  int cursor[8];
  int offpad[16];
  int ntiles;
  int pad[3];
  int texp[MAX_TILES];
};

__device__ __forceinline__ unsigned short f2bf(float f){
  unsigned u = __float_as_uint(f);
  u += 0x7FFFu + ((u>>16)&1u);          // RNE
  return (unsigned short)(u>>16);
}

__device__ __forceinline__ short8 pack8(float4 a, float4 b){
  short8 o;
  o[0]=(short)f2bf(a.x); o[1]=(short)f2bf(a.y); o[2]=(short)f2bf(a.z); o[3]=(short)f2bf(a.w);
  o[4]=(short)f2bf(b.x); o[5]=(short)f2bf(b.y); o[6]=(short)f2bf(b.z); o[7]=(short)f2bf(b.w);
  return o;
}

// ---------------- weight f32 -> bf16 ----------------
__global__ void __launch_bounds__(256)
cvt_kernel(const float* __restrict__ src, unsigned short* __restrict__ dst, int n){
  int i = (blockIdx.x*256 + threadIdx.x)*8;
  if(i >= n) return;
  float4 a = *(const float4*)(src+i);
  float4 b = *(const float4*)(src+i+4);
  *(short8*)(dst+i) = pack8(a,b);
}

// ---------------- gating: logits->softmax->top2 ----------------
__global__ void __launch_bounds__(256)
gate_kernel(const float* __restrict__ x, const float* __restrict__ gw,
            int* __restrict__ tok_e, float* __restrict__ tok_s,
            Ctrl* __restrict__ c, float* __restrict__ Ppart){
  __shared__ float gws[N_EXP*D_MODEL];
  __shared__ float pblk[4][8];
  __shared__ int cblk[8];
  int tid = threadIdx.x;
  for(int i=tid; i<N_EXP*D_MODEL; i+=256) gws[i]=gw[i];
  if(tid<8) cblk[tid]=0;
  __syncthreads();
  int wave = tid>>6, lane = tid&63;
  int t = blockIdx.x*4 + wave;
  const float* xr = x + (size_t)t*D_MODEL + lane*8;
  float4 xa = *(const float4*)xr;
  float4 xb = *(const float4*)(xr+4);
  float le[8];
  #pragma unroll
  for(int e=0;e<8;e++){
    const float* g = gws + e*D_MODEL + lane*8;
    float4 ga = *(const float4*)g;
    float4 gb = *(const float4*)(g+4);
    le[e] = xa.x*ga.x + xa.y*ga.y + xa.z*ga.z + xa.w*ga.w
          + xb.x*gb.x + xb.y*gb.y + xb.z*gb.z + xb.w*gb.w;
  }
  #pragma unroll
  for(int e=0;e<8;e++){
    float v = le[e];
    #pragma unroll
    for(int off=1; off<64; off<<=1) v += __shfl_xor(v, off);
    le[e]=v;
  }
  float mx = le[0];
  #pragma unroll
  for(int e=1;e<8;e++) mx = fmaxf(mx, le[e]);
  float p[8], s=0.f;
  #pragma unroll
  for(int e=0;e<8;e++){ p[e]=__expf(le[e]-mx); s+=p[e]; }
  float inv = 1.0f/s;
  #pragma unroll
  for(int e=0;e<8;e++) p[e]*=inv;
  // top-2, ties -> lower index (strict >)
  int e0=0; float s0=p[0];
  #pragma unroll
  for(int e=1;e<8;e++) if(p[e]>s0){e0=e;s0=p[e];}
  int e1=-1; float s1=-1.f;
  #pragma unroll
  for(int e=0;e<8;e++) if(e!=e0 && p[e]>s1){e1=e;s1=p[e];}
  if(lane==0){
    tok_e[2*t]=e0; tok_e[2*t+1]=e1;
    tok_s[2*t]=s0; tok_s[2*t+1]=s1;
    atomicAdd(&cblk[e0],1); atomicAdd(&cblk[e1],1);
    #pragma unroll
    for(int e=0;e<8;e++) pblk[wave][e]=p[e];
  }
  __syncthreads();
  if(tid<8){
    atomicAdd(&c->cnt[tid], cblk[tid]);
    Ppart[blockIdx.x*8+tid] = pblk[0][tid]+pblk[1][tid]+pblk[2][tid]+pblk[3][tid];
  }
}

// ---------------- scan: offsets, tile map, aux loss ----------------
__global__ void __launch_bounds__(256)
scan_kernel(Ctrl* __restrict__ c, const float* __restrict__ Ppart, float* __restrict__ out){
  __shared__ float red[256];
  __shared__ float tot[8];
  int tid = threadIdx.x;
  for(int e=0;e<8;e++){
    float v=0.f;
    for(int i=tid;i<2048;i+=256) v += Ppart[i*8+e];
    red[tid]=v; __syncthreads();
    for(int s=128;s>0;s>>=1){ if(tid<s) red[tid]+=red[tid+s]; __syncthreads(); }
    if(tid==0) tot[e]=red[0];
    __syncthreads();
  }
  if(tid==0){
    int o=0, tc=0;
    float aux=0.f;
    for(int e=0;e<8;e++){
      c->offpad[e]=o;
      int nt = (c->cnt[e]+TM-1)/TM;
      for(int i=0;i<nt;i++) c->texp[tc++]=e;
      o += nt*TM;
      c->cursor[e]=0;
      aux += ((float)c->cnt[e]/(float)NTOK) * (tot[e]/(float)NTOK);
    }
    c->offpad[8]=o;
    c->ntiles=tc;
    out[(size_t)NTOK*D_MODEL] = 8.0f*0.01f*aux;   // aux_loss slot
  }
}

// ---------------- scatter tokens into per-expert entry lists ----------------
__global__ void __launch_bounds__(256)
scatter_kernel(const int* __restrict__ tok_e, const float* __restrict__ tok_s,
               Ctrl* __restrict__ c, int* __restrict__ etok, float* __restrict__ escl){
  int t = blockIdx.x*256 + threadIdx.x;
  if(t >= NTOK) return;
  #pragma unroll
  for(int k=0;k<2;k++){
    int e = tok_e[2*t+k];
    int pos = atomicAdd(&c->cursor[e],1);
    int i = c->offpad[e]+pos;
    etok[i]=t; escl[i]=tok_s[2*t+k];
  }
}

// ---------------- phase A: G = silu(X W1^T) * (X V1^T), bf16 out ----------------
__global__ void __launch_bounds__(256)
expA_kernel(const float* __restrict__ x, const unsigned short* __restrict__ W1b,
            const unsigned short* __restrict__ V1b, const int* __restrict__ etok,
            const Ctrl* __restrict__ c, unsigned short* __restrict__ G){
  int tile = blockIdx.x;
  if(tile >= c->ntiles) return;
  int e = c->texp[tile];
  int base = tile*TM;
  int fbase = blockIdx.y*256;
  __shared__ short8 Xs[64*64];   // [64 rows][64 chunks of 8 bf16], XOR-swizzled
  int tid = threadIdx.x;
  {
    int m = tid>>2, q = tid&3;
    int tok = etok[base+m];
    const float* xr = x + (size_t)tok*D_MODEL + q*128;
    #pragma unroll
    for(int cc=0; cc<16; cc++){
      float4 a = *(const float4*)(xr + cc*8);
      float4 b = *(const float4*)(xr + cc*8 + 4);
      int chunk = q*16+cc;
      Xs[m*64 + (chunk ^ (m&7))] = pack8(a,b);
    }
  }
  __syncthreads();
  int wave = tid>>6, lane = tid&63, lrow = lane&15, lk = lane>>4;
  int fw = fbase + wave*64;
  const short8* W1p = (const short8*)W1b + (size_t)e*(D_FF*(D_MODEL/8));
  const short8* V1p = (const short8*)V1b + (size_t)e*(D_FF*(D_MODEL/8));
  f32x4 hacc[4][4], vacc[4][4];
  #pragma unroll
  for(int mi=0;mi<4;mi++)
    #pragma unroll
    for(int fj=0;fj<4;fj++){
      hacc[mi][fj] = (f32x4){0.f,0.f,0.f,0.f};
      vacc[mi][fj] = (f32x4){0.f,0.f,0.f,0.f};
    }
  for(int ks=0; ks<16; ks++){
    short8 a[4];
    #pragma unroll
    for(int mi=0;mi<4;mi++){
      int m = mi*16+lrow;
      a[mi] = Xs[m*64 + ((ks*4+lk) ^ (m&7))];
    }
    #pragma unroll
    for(int fj=0;fj<4;fj++){
      int f = fw + fj*16 + lrow;
      short8 b1 = W1p[(size_t)f*64 + ks*4+lk];
      short8 b2 = V1p[(size_t)f*64 + ks*4+lk];
      #pragma unroll
      for(int mi=0;mi<4;mi++){
        hacc[mi][fj] = __builtin_amdgcn_mfma_f32_16x16x32_bf16(a[mi], b1, hacc[mi][fj],0,0,0);
        vacc[mi][fj] = __builtin_amdgcn_mfma_f32_16x16x32_bf16(a[mi], b2, vacc[mi][fj],0,0,0);
      }
    }
  }
  #pragma unroll
  for(int mi=0;mi<4;mi++)
  #pragma unroll
  for(int fj=0;fj<4;fj++)
  #pragma unroll
  for(int r=0;r<4;r++){
    float h = hacc[mi][fj][r];
    float vv = vacc[mi][fj][r];
    float g = (h/(1.0f+__expf(-h)))*vv;   // silu(h)*v
    int m = mi*16 + lk*4 + r;             // C/D: row=(lane>>4)*4+reg
    int f = fw + fj*16 + lrow;            // C/D: col=lane&15
    G[(size_t)(base+m)*D_FF + f] = f2bf(g);
  }
}

// ---------------- phase B: Y = G W2^T, scatter-add scale*Y ----------------
__global__ void __launch_bounds__(256)
expB_kernel(const unsigned short* __restrict__ G, const unsigned short* __restrict__ W2b,
            const int* __restrict__ etok, const float* __restrict__ escl,
            const Ctrl* __restrict__ c, float* __restrict__ out){
  int tile = blockIdx.x;
  if(tile >= c->ntiles) return;
  int e = c->texp[tile];
  int base = tile*TM;
  int n0 = blockIdx.y*256;
  __shared__ short8 Gs[64*16];   // [64 rows][16 chunks], swizzled
  __shared__ int stok[64];
  __shared__ float sscl[64];
  int tid = threadIdx.x;
  if(tid<64){ stok[tid]=etok[base+tid]; sscl[tid]=escl[base+tid]; }
  int wave=tid>>6, lane=tid&63, lrow=lane&15, lk=lane>>4;
  int nb = n0 + wave*64;
  const short8* Gp  = (const short8*)G  + (size_t)base*(D_FF/8);
  const short8* W2p = (const short8*)W2b + (size_t)e*(D_MODEL*(D_FF/8));
  f32x4 y[4][4];
  #pragma unroll
  for(int mi=0;mi<4;mi++)
    #pragma unroll
    for(int nj=0;nj<4;nj++) y[mi][nj] = (f32x4){0.f,0.f,0.f,0.f};
  int sm = tid>>2, sq = tid&3;
  for(int kc=0; kc<16; kc++){
    __syncthreads();
    #pragma unroll
    for(int cc=0; cc<4; cc++){
      int ch = sq*4+cc;
      Gs[sm*16 + (ch ^ (sm&7))] = Gp[(size_t)sm*(D_FF/8) + kc*16 + ch];
    }
    __syncthreads();
    #pragma unroll
    for(int ks=0;ks<4;ks++){
      short8 a[4];
      #pragma unroll
      for(int mi=0;mi<4;mi++){
        int m = mi*16+lrow;
        a[mi] = Gs[m*16 + ((ks*4+lk) ^ (m&7))];
      }
      #pragma unroll
      for(int nj=0;nj<4;nj++){
        int n = nb + nj*16 + lrow;
        short8 b = W2p[(size_t)n*(D_FF/8) + kc*16 + ks*4+lk];
        #pragma unroll
        for(int mi=0;mi<4;mi++)
          y[mi][nj] = __builtin_amdgcn_mfma_f32_16x16x32_bf16(a[mi], b, y[mi][nj],0,0,0);
      }
    }
  }
  #pragma unroll
  for(int mi=0;mi<4;mi++)
  #pragma unroll
  for(int nj=0;nj<4;nj++)
  #pragma unroll
  for(int r=0;r<4;r++){
    int m = mi*16 + lk*4 + r;
    int n = nb + nj*16 + lrow;
    atomicAdd(out + (size_t)stok[m]*D_MODEL + n, sscl[m]*y[mi][nj][r]);
  }
}

extern "C" void kernel_launch(void* const* d_in, const int* in_sizes, int n_in,
                              void* d_out, int out_size, void* d_ws, size_t ws_size,
                              hipStream_t stream) {
  (void)in_sizes; (void)n_in;
  const float* x  = (const float*)d_in[0];
  const float* gw = (const float*)d_in[1];
  const float* W1 = (const float*)d_in[2];
  const float* V1 = (const float*)d_in[3];
  const float* W2 = (const float*)d_in[4];
  float* out = (float*)d_out;

  const size_t WSZ = (size_t)N_EXP*D_FF*D_MODEL;     // 8.39M elems per weight
  char* ws = (char*)d_ws;
  size_t off = 0;
  unsigned short* W1b = (unsigned short*)(ws+off); off += WSZ*2;
  unsigned short* V1b = (unsigned short*)(ws+off); off += WSZ*2;
  unsigned short* W2b = (unsigned short*)(ws+off); off += WSZ*2;
  unsigned short* G   = (unsigned short*)(ws+off); off += (size_t)NEPAD*D_FF*2;
  int*   etok  = (int*)(ws+off);   size_t entry_off = off; off += (size_t)NEPAD*4;
  float* escl  = (float*)(ws+off); off += (size_t)NEPAD*4;
  size_t entry_bytes = off - entry_off;
  int*   tok_e = (int*)(ws+off);   off += (size_t)NTOK*2*4;
  float* tok_s = (float*)(ws+off); off += (size_t)NTOK*2*4;
  float* Ppart = (float*)(ws+off); off += (size_t)2048*8*4;
  Ctrl*  ctrl  = (Ctrl*)(ws+off);  off += sizeof(Ctrl);
  if(ws_size < off) return;  // workspace too small -> will show as zero-output failure

  // zero output, entry lists (padding => token 0 / scale 0), control block
  hipMemsetAsync(d_out, 0, (size_t)out_size*sizeof(float), stream);
  hipMemsetAsync(ws+entry_off, 0, entry_bytes, stream);
  hipMemsetAsync(ctrl, 0, sizeof(Ctrl), stream);

  // weights -> bf16
  int nw = (int)WSZ;
  cvt_kernel<<<nw/(256*8), 256, 0, stream>>>(W1, W1b, nw);
  cvt_kernel<<<nw/(256*8), 256, 0, stream>>>(V1, V1b, nw);
  cvt_kernel<<<nw/(256*8), 256, 0, stream>>>(W2, W2b, nw);

  // gating -> scan -> scatter
  gate_kernel<<<NTOK/4, 256, 0, stream>>>(x, gw, tok_e, tok_s, ctrl, Ppart);
  scan_kernel<<<1, 256, 0, stream>>>(ctrl, Ppart, out);
  scatter_kernel<<<NTOK/256, 256, 0, stream>>>(tok_e, tok_s, ctrl, etok, escl);

  // experts
  expA_kernel<<<dim3(MAX_TILES, D_FF/256), 256, 0, stream>>>(x, W1b, V1b, etok, ctrl, G);
  expB_kernel<<<dim3(MAX_TILES, D_MODEL/256), 256, 0, stream>>>(G, W2b, etok, escl, ctrl, out);
}